// Round 1
// baseline (6915.046 us; speedup 1.0000x reference)
//
#include <hip/hip_runtime.h>
#include <hip/hip_fp16.h>

#define PLANE 262144   // 512*512
#define NC 21
#define NB 8
#define NPIX (NB*PLANE)

__device__ __forceinline__ float2 h2f(unsigned int u) {
  union { unsigned int u; __half2 h; } x; x.u = u;
  return __half22float2(x.h);
}
__device__ __forceinline__ unsigned int f2h(float a, float b) {
  union { unsigned int u; __half2 h; } x;
  x.h = __floats2half2_rn(a, b);
  return x.u;
}

// ---------------- prep: edge = exp(-|sobel(gray)|) ----------------
__global__ __launch_bounds__(256)
void k_edge(const float* __restrict__ img, __half* __restrict__ edge16) {
  int id = blockIdx.x*256 + threadIdx.x;
  int b = id >> 18;
  int rem = id & (PLANE-1);
  int y = rem >> 9, x = rem & 511;
  const float* ib = img + (size_t)b*3*PLANE;
  float g[3][3];
#pragma unroll
  for (int dy=0; dy<3; ++dy)
#pragma unroll
    for (int dx=0; dx<3; ++dx) {
      int yy = y+dy-1, xx = x+dx-1;
      float v = 0.f;
      if (yy>=0 && yy<512 && xx>=0 && xx<512) {
        int o = (yy<<9)|xx;
        v = 0.299f*ib[o] + 0.587f*ib[o+PLANE] + 0.114f*ib[o+2*PLANE];
      }
      g[dy][dx]=v;
    }
  float gxv = (g[0][2]-g[0][0]) + 2.f*(g[1][2]-g[1][0]) + (g[2][2]-g[2][0]);
  float gyv = (g[2][0]-g[0][0]) + 2.f*(g[2][1]-g[0][1]) + (g[2][2]-g[0][2]);
  float mag = sqrtf(gxv*gxv + gyv*gyv + 1e-6f);
  edge16[id] = __float2half(__expf(-mag));
}

// ---------------- prep: rnorm = 1/(avgpool3(edge)+1e-6) ----------------
__global__ __launch_bounds__(256)
void k_rnorm(const __half* __restrict__ edge16, float* __restrict__ rnorm) {
  int id = blockIdx.x*256 + threadIdx.x;
  int b = id >> 18;
  int rem = id & (PLANE-1);
  int y = rem >> 9, x = rem & 511;
  const __half* eb = edge16 + (size_t)b*PLANE;
  float s = 0.f;
#pragma unroll
  for (int dy=-1; dy<=1; ++dy)
#pragma unroll
    for (int dx=-1; dx<=1; ++dx) {
      int yy = y+dy, xx = x+dx;
      if (yy>=0 && yy<512 && xx>=0 && xx<512) s += __half2float(eb[(yy<<9)|xx]);
    }
  rnorm[id] = 1.f/(s*(1.f/9.f) + 1e-6f);
}

// ---------------- prep: compat == identity? ----------------
__global__ void k_flag(const float* __restrict__ compat, int* __restrict__ flag) {
  __shared__ int ok;
  if (threadIdx.x==0) ok = 1;
  __syncthreads();
  int bad = 0;
  for (int i = threadIdx.x; i < NC*NC; i += 256) {
    float exp = ((i/NC) == (i%NC)) ? 1.f : 0.f;
    if (compat[i] != exp) bad = 1;
  }
  if (bad) atomicAnd(&ok, 0);
  __syncthreads();
  if (threadIdx.x==0) flag[0] = ok;
}

// ---------------- prep: unary fp32 -> fp16 ----------------
__global__ __launch_bounds__(256)
void k_cvt(const float* __restrict__ u, __half* __restrict__ u16) {
  size_t q = (size_t)blockIdx.x*256 + threadIdx.x;
  float4 v = reinterpret_cast<const float4*>(u)[q];
  uint2 w; w.x = f2h(v.x, v.y); w.y = f2h(v.z, v.w);
  reinterpret_cast<uint2*>(u16)[q] = w;
}

// ---------------- Q0 = softmax(unary) -> fp16 ----------------
__global__ __launch_bounds__(256)
void k_softmax0(const float* __restrict__ unary, __half* __restrict__ Y) {
  int q = blockIdx.x*256 + threadIdx.x;           // quad id, [0, NPIX/4)
  int b = q >> 16;
  int rem = q & 65535;
  size_t base = (size_t)b*NC*(PLANE>>2) + rem;
  const float4* up = reinterpret_cast<const float4*>(unary);
  float v[NC][4];
  float mx0=-3e38f,mx1=-3e38f,mx2=-3e38f,mx3=-3e38f;
#pragma unroll
  for (int c=0;c<NC;++c) {
    float4 t = up[base + (size_t)c*(PLANE>>2)];
    v[c][0]=t.x; v[c][1]=t.y; v[c][2]=t.z; v[c][3]=t.w;
    mx0=fmaxf(mx0,t.x); mx1=fmaxf(mx1,t.y); mx2=fmaxf(mx2,t.z); mx3=fmaxf(mx3,t.w);
  }
  float s0=0,s1=0,s2=0,s3=0;
#pragma unroll
  for (int c=0;c<NC;++c) {
    float e0=__expf(v[c][0]-mx0), e1=__expf(v[c][1]-mx1);
    float e2=__expf(v[c][2]-mx2), e3=__expf(v[c][3]-mx3);
    v[c][0]=e0; v[c][1]=e1; v[c][2]=e2; v[c][3]=e3;
    s0+=e0; s1+=e1; s2+=e2; s3+=e3;
  }
  float r0=1.f/s0, r1=1.f/s1, r2=1.f/s2, r3=1.f/s3;
  uint2* yp = reinterpret_cast<uint2*>(Y);
#pragma unroll
  for (int c=0;c<NC;++c) {
    uint2 w; w.x=f2h(v[c][0]*r0, v[c][1]*r1); w.y=f2h(v[c][2]*r2, v[c][3]*r3);
    yp[base + (size_t)c*(PLANE>>2)] = w;
  }
}

// ---------------- fused CRF iteration ----------------
// R2: 2 px/thread (was 4), 512-thread blocks, tile 64x16.
// R1 post-mortem: with 4 px/thread the live set (msgr[21][4]=84 + cs8/ce8/f/e=32
// + staging) pegged VGPR at the 256 arch max -> ~500 MB/iter of scratch spill
// traffic (WRITE_SIZE 602 MB vs 88 MB real output), occupancy 11.8%, VALUBusy 10%.
// Halving per-thread state (msgr[21][2]=42) targets VGPR ~128, zero spill,
// 3-4 waves/SIMD.

#define LOAD_U2(c, u0,u1) \
  float u0,u1; \
  if (U16) { unsigned int w_ = reinterpret_cast<const unsigned int*>(uptr)[hbase + (size_t)(c)*ch]; \
    float2 t_=h2f(w_); u0=t_.x; u1=t_.y; } \
  else { float2 v_ = reinterpret_cast<const float2*>(uptr)[hbase + (size_t)(c)*ch]; \
    u0=v_.x; u1=v_.y; }

#define ACCUM_COMPAT2(c, a0,a1) \
  float a0=0.f,a1=0.f; \
  _Pragma("unroll") \
  for (int d=0; d<NC; ++d) { float cf_ = compat[(c)*NC+d]; \
    a0 += cf_*msgr[d][0]; a1 += cf_*msgr[d][1]; }

template<bool U16, bool OUTF32>
__global__ __launch_bounds__(512)
void k_iter(const __half* __restrict__ Qin,
            void* __restrict__ Qout,
            const void* __restrict__ uptr,
            const __half* __restrict__ edge16,
            const float* __restrict__ rnorm,
            const float* __restrict__ swp,
            const float* __restrict__ bwp,
            const float* __restrict__ compat,
            const int* __restrict__ flag)
{
  __shared__ __half qt[20][72];
  __shared__ __half et[20][72];

  const int tid = threadIdx.x;
  const int tx = tid & 31;        // 32 threads across 64 px, 2 px each
  const int ty = tid >> 5;        // 16 rows
  const int x0 = blockIdx.x << 6;
  const int y0 = blockIdx.y << 4;
  const int b  = blockIdx.z;
  const __half HZERO = __float2half(0.f);

  // staging decomposition: 20 rows x 68 cols = 1360 halves, <=3 slots/thread
  int sdst[3], ssrc[3];
#pragma unroll
  for (int j=0;j<3;++j) {
    int idx = tid + j*512;
    if (idx < 1360) {
      int r = idx / 68;
      int i = idx - r*68;
      int sy = y0 - 2 + r;
      int sx = x0 - 2 + i;
      sdst[j] = r*72 + i;
      ssrc[j] = (sy>=0 && sy<512 && sx>=0 && sx<512) ? ((sy<<9)|sx) : -1;
    } else { sdst[j] = -1; ssrc[j] = -1; }
  }

  { // edge tile once per block
    const __half* ep = edge16 + (size_t)b*PLANE;
    __half* etf = &et[0][0];
#pragma unroll
    for (int j=0;j<3;++j) if (sdst[j]>=0) etf[sdst[j]] = (ssrc[j]>=0) ? ep[ssrc[j]] : HZERO;
  }

  const float sw  = fmaxf(swp[0], 0.f);
  const float bw  = fmaxf(bwp[0], 0.f);
  const float csw = sw * 0.04f;          // sw/25
  const float b9  = bw * (1.f/9.f);      // bw/9

  const int gy  = y0 + ty;
  const int gx  = x0 + (tx<<1);
  const int pix = (gy<<9) | gx;
  const int lx  = tx << 1;               // LDS col of first owned px (halo offset 2 built into indices below)

  const float2 rn = *reinterpret_cast<const float2*>(rnorm + (size_t)b*PLANE + pix);
  const float cb0 = b9*rn.x, cb1 = b9*rn.y;

  float msgr[NC][2];
  const __half* qb  = Qin + (size_t)b*NC*PLANE;
  __half* qtf = &qt[0][0];

#pragma unroll
  for (int c=0;c<NC;++c) {
    __syncthreads();   // protect qt from previous channel's readers
    const __half* qp = qb + (size_t)c*PLANE;
#pragma unroll
    for (int j=0;j<3;++j) if (sdst[j]>=0) qtf[sdst[j]] = (ssrc[j]>=0) ? qp[ssrc[j]] : HZERO;
    __syncthreads();

    // column sums: cs over LDS cols lx..lx+5 (global gx-2..gx+3),
    // edge-weighted ce over cols lx+1..lx+4 (global gx-1..gx+2)
    float cs0=0,cs1=0,cs2=0,cs3=0,cs4=0,cs5=0;
    float ce0=0,ce1=0,ce2=0,ce3=0;
#pragma unroll
    for (int dy=0;dy<5;++dy) {
      const unsigned int* qrow = reinterpret_cast<const unsigned int*>(&qt[ty+dy][lx]);
      float2 t0 = h2f(qrow[0]);
      float2 t1 = h2f(qrow[1]);
      float2 t2 = h2f(qrow[2]);
      cs0+=t0.x; cs1+=t0.y; cs2+=t1.x; cs3+=t1.y; cs4+=t2.x; cs5+=t2.y;
      if (dy>=1 && dy<=3) {
        const unsigned int* erow = reinterpret_cast<const unsigned int*>(&et[ty+dy][lx]);
        float2 e0 = h2f(erow[0]);
        float2 e1 = h2f(erow[1]);
        float2 e2 = h2f(erow[2]);
        ce0 += t0.y*e0.y;   // gx-1
        ce1 += t1.x*e1.x;   // gx
        ce2 += t1.y*e1.y;   // gx+1
        ce3 += t2.x*e2.x;   // gx+2
      }
    }
    float v0 = cs0+cs1+cs2+cs3+cs4;      // 5-wide window @ gx
    float v1 = v0 - cs0 + cs5;           // @ gx+1
    float w0 = ce0+ce1+ce2;              // 3-wide window @ gx
    float w1 = ce1+ce2+ce3;              // @ gx+1
    msgr[c][0] = csw*v0 + cb0*w0;
    msgr[c][1] = csw*v1 + cb1*w1;
  }

  // ---- phase 2: (optional compat) + softmax over channels, in registers ----
  const int fl = flag[0];
  const size_t hbase = (((size_t)b*NC*PLANE) + (size_t)pix) >> 1;  // half2 / float2 units
  const size_t ch = PLANE >> 1;
  float mx0=-3e38f, mx1=-3e38f;

  if (fl) {   // identity compat fast path
#pragma unroll
    for (int c=0;c<NC;++c) {
      LOAD_U2(c, u0,u1)
      msgr[c][0] = u0 - msgr[c][0];
      msgr[c][1] = u1 - msgr[c][1];
      mx0=fmaxf(mx0,msgr[c][0]); mx1=fmaxf(mx1,msgr[c][1]);
    }
    float s0=0,s1=0;
#pragma unroll
    for (int c=0;c<NC;++c) {
      float e0=__expf(msgr[c][0]-mx0), e1=__expf(msgr[c][1]-mx1);
      msgr[c][0]=e0; msgr[c][1]=e1;
      s0+=e0; s1+=e1;
    }
    float r0=1.f/s0, r1=1.f/s1;
#pragma unroll
    for (int c=0;c<NC;++c) {
      float o0=msgr[c][0]*r0, o1=msgr[c][1]*r1;
      if (OUTF32) {
        reinterpret_cast<float2*>(Qout)[hbase + (size_t)c*ch] = make_float2(o0,o1);
      } else {
        reinterpret_cast<unsigned int*>(Qout)[hbase + (size_t)c*ch] = f2h(o0,o1);
      }
    }
  } else {    // general compat: recompute logits per pass (register-light)
#pragma unroll 1
    for (int c=0;c<NC;++c) {
      ACCUM_COMPAT2(c, a0,a1)
      LOAD_U2(c, u0,u1)
      mx0=fmaxf(mx0,u0-a0); mx1=fmaxf(mx1,u1-a1);
    }
    float s0=0,s1=0;
#pragma unroll 1
    for (int c=0;c<NC;++c) {
      ACCUM_COMPAT2(c, a0,a1)
      LOAD_U2(c, u0,u1)
      s0+=__expf(u0-a0-mx0); s1+=__expf(u1-a1-mx1);
    }
    float r0=1.f/s0, r1=1.f/s1;
#pragma unroll 1
    for (int c=0;c<NC;++c) {
      ACCUM_COMPAT2(c, a0,a1)
      LOAD_U2(c, u0,u1)
      float o0=__expf(u0-a0-mx0)*r0, o1=__expf(u1-a1-mx1)*r1;
      if (OUTF32) {
        reinterpret_cast<float2*>(Qout)[hbase + (size_t)c*ch] = make_float2(o0,o1);
      } else {
        reinterpret_cast<unsigned int*>(Qout)[hbase + (size_t)c*ch] = f2h(o0,o1);
      }
    }
  }
}

extern "C" void kernel_launch(void* const* d_in, const int* in_sizes, int n_in,
                              void* d_out, int out_size, void* d_ws, size_t ws_size,
                              hipStream_t stream)
{
  const float* unary  = (const float*)d_in[0];
  const float* image  = (const float*)d_in[1];
  const float* compat = (const float*)d_in[2];
  const float* swp    = (const float*)d_in[3];
  const float* bwp    = (const float*)d_in[4];

  // ws layout (bytes): X fp16 Q buffer | edge16 | rnorm | flag | (opt) u16
  char* ws = (char*)d_ws;
  __half* X      = (__half*)(ws + 0);            // 88,080,384 B
  __half* edge16 = (__half*)(ws + 88080384);     //  4,194,304 B
  float*  rnorm  = (float*) (ws + 92274688);     //  8,388,608 B
  int*    flag   = (int*)   (ws + 100663296);    //        256 B
  __half* u16    = (__half*)(ws + 100663552);    // 88,080,384 B (optional)
  if (ws_size < (size_t)100663552) return;       // cannot run without scratch
  const bool use_u16 = (ws_size >= (size_t)188743936);

  __half* Y  = (__half*)d_out;   // d_out doubles as fp16 scratch during iters
  float* out = (float*)d_out;

  k_edge   <<<dim3(8192), dim3(256), 0, stream>>>(image, edge16);
  k_rnorm  <<<dim3(8192), dim3(256), 0, stream>>>(edge16, rnorm);
  k_flag   <<<dim3(1),    dim3(256), 0, stream>>>(compat, flag);
  if (use_u16) k_cvt<<<dim3(43008), dim3(256), 0, stream>>>(unary, u16);
  k_softmax0<<<dim3(2048), dim3(256), 0, stream>>>(unary, Y);

  const void* up = use_u16 ? (const void*)u16 : (const void*)unary;
  dim3 gi(8, 32, NB), bi(512);
  // Q0 -> Y(d_out,fp16); odd iters Y->X; even iters X->Y; iter10 X -> d_out fp32
  for (int it = 1; it <= 10; ++it) {
    const __half* qin = (it & 1) ? Y : X;
    if (it == 10) {
      if (use_u16) k_iter<true , true ><<<gi,bi,0,stream>>>(qin,(void*)out,up,edge16,rnorm,swp,bwp,compat,flag);
      else         k_iter<false, true ><<<gi,bi,0,stream>>>(qin,(void*)out,up,edge16,rnorm,swp,bwp,compat,flag);
    } else {
      void* qout = (it & 1) ? (void*)X : (void*)Y;
      if (use_u16) k_iter<true , false><<<gi,bi,0,stream>>>(qin,qout,up,edge16,rnorm,swp,bwp,compat,flag);
      else         k_iter<false, false><<<gi,bi,0,stream>>>(qin,qout,up,edge16,rnorm,swp,bwp,compat,flag);
    }
  }
}

// Round 3
// 3776.060 us; speedup vs baseline: 1.8313x; 1.8313x over previous
//
#include <hip/hip_runtime.h>
#include <hip/hip_fp16.h>

#define PLANE 262144   // 512*512
#define NC 21
#define NB 8
#define NPIX (NB*PLANE)

__device__ __forceinline__ float2 h2f(unsigned int u) {
  union { unsigned int u; __half2 h; } x; x.u = u;
  return __half22float2(x.h);
}
__device__ __forceinline__ unsigned int f2h(float a, float b) {
  union { unsigned int u; __half2 h; } x;
  x.h = __floats2half2_rn(a, b);
  return x.u;
}

// ---------------- prep: edge = exp(-|sobel(gray)|) ----------------
__global__ __launch_bounds__(256)
void k_edge(const float* __restrict__ img, __half* __restrict__ edge16) {
  int id = blockIdx.x*256 + threadIdx.x;
  int b = id >> 18;
  int rem = id & (PLANE-1);
  int y = rem >> 9, x = rem & 511;
  const float* ib = img + (size_t)b*3*PLANE;
  float g[3][3];
#pragma unroll
  for (int dy=0; dy<3; ++dy)
#pragma unroll
    for (int dx=0; dx<3; ++dx) {
      int yy = y+dy-1, xx = x+dx-1;
      float v = 0.f;
      if (yy>=0 && yy<512 && xx>=0 && xx<512) {
        int o = (yy<<9)|xx;
        v = 0.299f*ib[o] + 0.587f*ib[o+PLANE] + 0.114f*ib[o+2*PLANE];
      }
      g[dy][dx]=v;
    }
  float gxv = (g[0][2]-g[0][0]) + 2.f*(g[1][2]-g[1][0]) + (g[2][2]-g[2][0]);
  float gyv = (g[2][0]-g[0][0]) + 2.f*(g[2][1]-g[0][1]) + (g[2][2]-g[0][2]);
  float mag = sqrtf(gxv*gxv + gyv*gyv + 1e-6f);
  edge16[id] = __float2half(__expf(-mag));
}

// ---------------- prep: rnorm = 1/(avgpool3(edge)+1e-6) ----------------
__global__ __launch_bounds__(256)
void k_rnorm(const __half* __restrict__ edge16, float* __restrict__ rnorm) {
  int id = blockIdx.x*256 + threadIdx.x;
  int b = id >> 18;
  int rem = id & (PLANE-1);
  int y = rem >> 9, x = rem & 511;
  const __half* eb = edge16 + (size_t)b*PLANE;
  float s = 0.f;
#pragma unroll
  for (int dy=-1; dy<=1; ++dy)
#pragma unroll
    for (int dx=-1; dx<=1; ++dx) {
      int yy = y+dy, xx = x+dx;
      if (yy>=0 && yy<512 && xx>=0 && xx<512) s += __half2float(eb[(yy<<9)|xx]);
    }
  rnorm[id] = 1.f/(s*(1.f/9.f) + 1e-6f);
}

// ---------------- prep: compat == identity? ----------------
__global__ void k_flag(const float* __restrict__ compat, int* __restrict__ flag) {
  __shared__ int ok;
  if (threadIdx.x==0) ok = 1;
  __syncthreads();
  int bad = 0;
  for (int i = threadIdx.x; i < NC*NC; i += 256) {
    float exp = ((i/NC) == (i%NC)) ? 1.f : 0.f;
    if (compat[i] != exp) bad = 1;
  }
  if (bad) atomicAnd(&ok, 0);
  __syncthreads();
  if (threadIdx.x==0) flag[0] = ok;
}

// ---------------- prep: unary fp32 -> fp16 ----------------
__global__ __launch_bounds__(256)
void k_cvt(const float* __restrict__ u, __half* __restrict__ u16) {
  size_t q = (size_t)blockIdx.x*256 + threadIdx.x;
  float4 v = reinterpret_cast<const float4*>(u)[q];
  uint2 w; w.x = f2h(v.x, v.y); w.y = f2h(v.z, v.w);
  reinterpret_cast<uint2*>(u16)[q] = w;
}

// ---------------- Q0 = softmax(unary) -> fp16 ----------------
__global__ __launch_bounds__(256)
void k_softmax0(const float* __restrict__ unary, __half* __restrict__ Y) {
  int q = blockIdx.x*256 + threadIdx.x;           // quad id, [0, NPIX/4)
  int b = q >> 16;
  int rem = q & 65535;
  size_t base = (size_t)b*NC*(PLANE>>2) + rem;
  const float4* up = reinterpret_cast<const float4*>(unary);
  float v[NC][4];
  float mx0=-3e38f,mx1=-3e38f,mx2=-3e38f,mx3=-3e38f;
#pragma unroll
  for (int c=0;c<NC;++c) {
    float4 t = up[base + (size_t)c*(PLANE>>2)];
    v[c][0]=t.x; v[c][1]=t.y; v[c][2]=t.z; v[c][3]=t.w;
    mx0=fmaxf(mx0,t.x); mx1=fmaxf(mx1,t.y); mx2=fmaxf(mx2,t.z); mx3=fmaxf(mx3,t.w);
  }
  float s0=0,s1=0,s2=0,s3=0;
#pragma unroll
  for (int c=0;c<NC;++c) {
    float e0=__expf(v[c][0]-mx0), e1=__expf(v[c][1]-mx1);
    float e2=__expf(v[c][2]-mx2), e3=__expf(v[c][3]-mx3);
    v[c][0]=e0; v[c][1]=e1; v[c][2]=e2; v[c][3]=e3;
    s0+=e0; s1+=e1; s2+=e2; s3+=e3;
  }
  float r0=1.f/s0, r1=1.f/s1, r2=1.f/s2, r3=1.f/s3;
  uint2* yp = reinterpret_cast<uint2*>(Y);
#pragma unroll
  for (int c=0;c<NC;++c) {
    uint2 w; w.x=f2h(v[c][0]*r0, v[c][1]*r1); w.y=f2h(v[c][2]*r2, v[c][3]*r3);
    yp[base + (size_t)c*(PLANE>>2)] = w;
  }
}

// ---------------- fused CRF iteration ----------------
// R3 (resubmit of R2 after infra failure): stage ALL 21 channel tiles to LDS
// first (63.4 KB), ONE barrier, then a pure-LDS unrolled compute loop.
// R1/R2 post-mortem: interleaving global staging loads with the unrolled
// 21-channel compute let the compiler software-pipeline loads across channels
// -> live set blew past the VGPR cap -> 0.5-1.1 GB/iter scratch traffic
// (R2: WRITE 1155 MB vs 88 MB real). Separating memory phase from compute
// phase bounds the compute live set to msgr(42)+temps(~25)+edge regs(12)
// ~= 100 VGPRs. 2 px/thread, 512 threads, tile 64x16, 2 blocks/CU (LDS-lim).

#define LOAD_U2(c, u0,u1) \
  float u0,u1; \
  if (U16) { unsigned int w_ = reinterpret_cast<const unsigned int*>(uptr)[hbase + (size_t)(c)*ch]; \
    float2 t_=h2f(w_); u0=t_.x; u1=t_.y; } \
  else { float2 v_ = reinterpret_cast<const float2*>(uptr)[hbase + (size_t)(c)*ch]; \
    u0=v_.x; u1=v_.y; }

#define ACCUM_COMPAT2(c, a0,a1) \
  float a0=0.f,a1=0.f; \
  _Pragma("unroll") \
  for (int d=0; d<NC; ++d) { float cf_ = compat[(c)*NC+d]; \
    a0 += cf_*msgr[d][0]; a1 += cf_*msgr[d][1]; }

#define CROW 72            // LDS row stride (halves)
#define CTILE (20*CROW)    // halves per channel tile (20 rows)

template<bool U16, bool OUTF32>
__global__ __launch_bounds__(512)
void k_iter(const __half* __restrict__ Qin,
            void* __restrict__ Qout,
            const void* __restrict__ uptr,
            const __half* __restrict__ edge16,
            const float* __restrict__ rnorm,
            const float* __restrict__ swp,
            const float* __restrict__ bwp,
            const float* __restrict__ compat,
            const int* __restrict__ flag)
{
  __shared__ __half qt21[NC*CTILE];   // 21 x 20 x 72 halves = 60480 B
  __shared__ __half et[CTILE];        // 20 x 72 halves      =  2880 B

  const int tid = threadIdx.x;
  const int tx = tid & 31;        // 32 threads across 64 px, 2 px each
  const int ty = tid >> 5;        // 16 rows
  const int x0 = blockIdx.x << 6;
  const int y0 = blockIdx.y << 4;
  const int b  = blockIdx.z;
  const __half HZERO = __float2half(0.f);

  // staging decomposition: 20 rows x 68 cols = 1360 halves, <=3 slots/thread
  int sdst[3], ssrc[3];
#pragma unroll
  for (int j=0;j<3;++j) {
    int idx = tid + j*512;
    if (idx < 1360) {
      int r = idx / 68;
      int i = idx - r*68;
      int sy = y0 - 2 + r;
      int sx = x0 - 2 + i;
      sdst[j] = r*CROW + i;
      ssrc[j] = (sy>=0 && sy<512 && sx>=0 && sx<512) ? ((sy<<9)|sx) : -1;
    } else { sdst[j] = -1; ssrc[j] = -1; }
  }

  // ---- memory phase: stage edge tile + ALL 21 channel tiles, one barrier ----
  {
    const __half* ep = edge16 + (size_t)b*PLANE;
#pragma unroll
    for (int j=0;j<3;++j) if (sdst[j]>=0) et[sdst[j]] = (ssrc[j]>=0) ? ep[ssrc[j]] : HZERO;
  }
  const __half* qb = Qin + (size_t)b*NC*PLANE;
#pragma unroll 3
  for (int c=0;c<NC;++c) {
    const __half* qp = qb + (size_t)c*PLANE;
    __half* dst = qt21 + c*CTILE;
#pragma unroll
    for (int j=0;j<3;++j) if (sdst[j]>=0) dst[sdst[j]] = (ssrc[j]>=0) ? qp[ssrc[j]] : HZERO;
  }
  __syncthreads();

  const float sw  = fmaxf(swp[0], 0.f);
  const float bw  = fmaxf(bwp[0], 0.f);
  const float csw = sw * 0.04f;          // sw/25
  const float b9  = bw * (1.f/9.f);      // bw/9

  const int gy  = y0 + ty;
  const int gx  = x0 + (tx<<1);
  const int pix = (gy<<9) | gx;
  const int lx  = tx << 1;               // LDS col of first owned px

  const float2 rn = *reinterpret_cast<const float2*>(rnorm + (size_t)b*PLANE + pix);
  const float cb0 = b9*rn.x, cb1 = b9*rn.y;

  // hoist edge window into registers once (channel-invariant):
  // rows ty+1..ty+3, cols lx+1..lx+4
  float ew[3][4];
#pragma unroll
  for (int dy=0;dy<3;++dy) {
    const unsigned int* erow = reinterpret_cast<const unsigned int*>(et + (ty+1+dy)*CROW + lx);
    float2 e0 = h2f(erow[0]);
    float2 e1 = h2f(erow[1]);
    float2 e2 = h2f(erow[2]);
    ew[dy][0]=e0.y; ew[dy][1]=e1.x; ew[dy][2]=e1.y; ew[dy][3]=e2.x;
  }

  // ---- compute phase: pure LDS reads, no global traffic ----
  float msgr[NC][2];
  const __half* qrow0 = qt21 + ty*CROW + lx;

#pragma unroll
  for (int c=0;c<NC;++c) {
    float cs0=0,cs1=0,cs2=0,cs3=0,cs4=0,cs5=0;
    float ce0=0,ce1=0,ce2=0,ce3=0;
#pragma unroll
    for (int dy=0;dy<5;++dy) {
      const unsigned int* qrow = reinterpret_cast<const unsigned int*>(qrow0 + c*CTILE + dy*CROW);
      float2 t0 = h2f(qrow[0]);
      float2 t1 = h2f(qrow[1]);
      float2 t2 = h2f(qrow[2]);
      cs0+=t0.x; cs1+=t0.y; cs2+=t1.x; cs3+=t1.y; cs4+=t2.x; cs5+=t2.y;
      if (dy>=1 && dy<=3) {
        ce0 += t0.y*ew[dy-1][0];   // gx-1
        ce1 += t1.x*ew[dy-1][1];   // gx
        ce2 += t1.y*ew[dy-1][2];   // gx+1
        ce3 += t2.x*ew[dy-1][3];   // gx+2
      }
    }
    float v0 = cs0+cs1+cs2+cs3+cs4;      // 5-wide window @ gx
    float v1 = v0 - cs0 + cs5;           // @ gx+1
    float w0 = ce0+ce1+ce2;              // 3-wide window @ gx
    float w1 = ce1+ce2+ce3;              // @ gx+1
    msgr[c][0] = csw*v0 + cb0*w0;
    msgr[c][1] = csw*v1 + cb1*w1;
  }

  // ---- phase 2: (optional compat) + softmax over channels, in registers ----
  const int fl = flag[0];
  const size_t hbase = (((size_t)b*NC*PLANE) + (size_t)pix) >> 1;  // half2 / float2 units
  const size_t ch = PLANE >> 1;
  float mx0=-3e38f, mx1=-3e38f;

  if (fl) {   // identity compat fast path
#pragma unroll
    for (int c=0;c<NC;++c) {
      LOAD_U2(c, u0,u1)
      msgr[c][0] = u0 - msgr[c][0];
      msgr[c][1] = u1 - msgr[c][1];
      mx0=fmaxf(mx0,msgr[c][0]); mx1=fmaxf(mx1,msgr[c][1]);
    }
    float s0=0,s1=0;
#pragma unroll
    for (int c=0;c<NC;++c) {
      float e0=__expf(msgr[c][0]-mx0), e1=__expf(msgr[c][1]-mx1);
      msgr[c][0]=e0; msgr[c][1]=e1;
      s0+=e0; s1+=e1;
    }
    float r0=1.f/s0, r1=1.f/s1;
#pragma unroll
    for (int c=0;c<NC;++c) {
      float o0=msgr[c][0]*r0, o1=msgr[c][1]*r1;
      if (OUTF32) {
        reinterpret_cast<float2*>(Qout)[hbase + (size_t)c*ch] = make_float2(o0,o1);
      } else {
        reinterpret_cast<unsigned int*>(Qout)[hbase + (size_t)c*ch] = f2h(o0,o1);
      }
    }
  } else {    // general compat: recompute logits per pass (register-light)
#pragma unroll 1
    for (int c=0;c<NC;++c) {
      ACCUM_COMPAT2(c, a0,a1)
      LOAD_U2(c, u0,u1)
      mx0=fmaxf(mx0,u0-a0); mx1=fmaxf(mx1,u1-a1);
    }
    float s0=0,s1=0;
#pragma unroll 1
    for (int c=0;c<NC;++c) {
      ACCUM_COMPAT2(c, a0,a1)
      LOAD_U2(c, u0,u1)
      s0+=__expf(u0-a0-mx0); s1+=__expf(u1-a1-mx1);
    }
    float r0=1.f/s0, r1=1.f/s1;
#pragma unroll 1
    for (int c=0;c<NC;++c) {
      ACCUM_COMPAT2(c, a0,a1)
      LOAD_U2(c, u0,u1)
      float o0=__expf(u0-a0-mx0)*r0, o1=__expf(u1-a1-mx1)*r1;
      if (OUTF32) {
        reinterpret_cast<float2*>(Qout)[hbase + (size_t)c*ch] = make_float2(o0,o1);
      } else {
        reinterpret_cast<unsigned int*>(Qout)[hbase + (size_t)c*ch] = f2h(o0,o1);
      }
    }
  }
}

extern "C" void kernel_launch(void* const* d_in, const int* in_sizes, int n_in,
                              void* d_out, int out_size, void* d_ws, size_t ws_size,
                              hipStream_t stream)
{
  const float* unary  = (const float*)d_in[0];
  const float* image  = (const float*)d_in[1];
  const float* compat = (const float*)d_in[2];
  const float* swp    = (const float*)d_in[3];
  const float* bwp    = (const float*)d_in[4];

  // ws layout (bytes): X fp16 Q buffer | edge16 | rnorm | flag | (opt) u16
  char* ws = (char*)d_ws;
  __half* X      = (__half*)(ws + 0);            // 88,080,384 B
  __half* edge16 = (__half*)(ws + 88080384);     //  4,194,304 B
  float*  rnorm  = (float*) (ws + 92274688);     //  8,388,608 B
  int*    flag   = (int*)   (ws + 100663296);    //        256 B
  __half* u16    = (__half*)(ws + 100663552);    // 88,080,384 B (optional)
  if (ws_size < (size_t)100663552) return;       // cannot run without scratch
  const bool use_u16 = (ws_size >= (size_t)188743936);

  __half* Y  = (__half*)d_out;   // d_out doubles as fp16 scratch during iters
  float* out = (float*)d_out;

  k_edge   <<<dim3(8192), dim3(256), 0, stream>>>(image, edge16);
  k_rnorm  <<<dim3(8192), dim3(256), 0, stream>>>(edge16, rnorm);
  k_flag   <<<dim3(1),    dim3(256), 0, stream>>>(compat, flag);
  if (use_u16) k_cvt<<<dim3(43008), dim3(256), 0, stream>>>(unary, u16);
  k_softmax0<<<dim3(2048), dim3(256), 0, stream>>>(unary, Y);

  const void* up = use_u16 ? (const void*)u16 : (const void*)unary;
  dim3 gi(8, 32, NB), bi(512);
  // Q0 -> Y(d_out,fp16); odd iters Y->X; even iters X->Y; iter10 X -> d_out fp32
  for (int it = 1; it <= 10; ++it) {
    const __half* qin = (it & 1) ? Y : X;
    if (it == 10) {
      if (use_u16) k_iter<true , true ><<<gi,bi,0,stream>>>(qin,(void*)out,up,edge16,rnorm,swp,bwp,compat,flag);
      else         k_iter<false, true ><<<gi,bi,0,stream>>>(qin,(void*)out,up,edge16,rnorm,swp,bwp,compat,flag);
    } else {
      void* qout = (it & 1) ? (void*)X : (void*)Y;
      if (use_u16) k_iter<true , false><<<gi,bi,0,stream>>>(qin,qout,up,edge16,rnorm,swp,bwp,compat,flag);
      else         k_iter<false, false><<<gi,bi,0,stream>>>(qin,qout,up,edge16,rnorm,swp,bwp,compat,flag);
    }
  }
}

// Round 4
// 2839.091 us; speedup vs baseline: 2.4357x; 1.3300x over previous
//
#include <hip/hip_runtime.h>
#include <hip/hip_fp16.h>

#define PLANE 262144   // 512*512
#define NC 21
#define NB 8
#define NPIX (NB*PLANE)

__device__ __forceinline__ float2 h2f(unsigned int u) {
  union { unsigned int u; __half2 h; } x; x.u = u;
  return __half22float2(x.h);
}
__device__ __forceinline__ unsigned int f2h(float a, float b) {
  union { unsigned int u; __half2 h; } x;
  x.h = __floats2half2_rn(a, b);
  return x.u;
}

// ---------------- prep: edge = exp(-|sobel(gray)|) ----------------
__global__ __launch_bounds__(256)
void k_edge(const float* __restrict__ img, __half* __restrict__ edge16) {
  int id = blockIdx.x*256 + threadIdx.x;
  int b = id >> 18;
  int rem = id & (PLANE-1);
  int y = rem >> 9, x = rem & 511;
  const float* ib = img + (size_t)b*3*PLANE;
  float g[3][3];
#pragma unroll
  for (int dy=0; dy<3; ++dy)
#pragma unroll
    for (int dx=0; dx<3; ++dx) {
      int yy = y+dy-1, xx = x+dx-1;
      float v = 0.f;
      if (yy>=0 && yy<512 && xx>=0 && xx<512) {
        int o = (yy<<9)|xx;
        v = 0.299f*ib[o] + 0.587f*ib[o+PLANE] + 0.114f*ib[o+2*PLANE];
      }
      g[dy][dx]=v;
    }
  float gxv = (g[0][2]-g[0][0]) + 2.f*(g[1][2]-g[1][0]) + (g[2][2]-g[2][0]);
  float gyv = (g[2][0]-g[0][0]) + 2.f*(g[2][1]-g[0][1]) + (g[2][2]-g[0][2]);
  float mag = sqrtf(gxv*gxv + gyv*gyv + 1e-6f);
  edge16[id] = __float2half(__expf(-mag));
}

// ---------------- prep: rnorm = 1/(avgpool3(edge)+1e-6) ----------------
__global__ __launch_bounds__(256)
void k_rnorm(const __half* __restrict__ edge16, float* __restrict__ rnorm) {
  int id = blockIdx.x*256 + threadIdx.x;
  int b = id >> 18;
  int rem = id & (PLANE-1);
  int y = rem >> 9, x = rem & 511;
  const __half* eb = edge16 + (size_t)b*PLANE;
  float s = 0.f;
#pragma unroll
  for (int dy=-1; dy<=1; ++dy)
#pragma unroll
    for (int dx=-1; dx<=1; ++dx) {
      int yy = y+dy, xx = x+dx;
      if (yy>=0 && yy<512 && xx>=0 && xx<512) s += __half2float(eb[(yy<<9)|xx]);
    }
  rnorm[id] = 1.f/(s*(1.f/9.f) + 1e-6f);
}

// ---------------- prep: compat == identity? ----------------
__global__ void k_flag(const float* __restrict__ compat, int* __restrict__ flag) {
  __shared__ int ok;
  if (threadIdx.x==0) ok = 1;
  __syncthreads();
  int bad = 0;
  for (int i = threadIdx.x; i < NC*NC; i += 256) {
    float exp = ((i/NC) == (i%NC)) ? 1.f : 0.f;
    if (compat[i] != exp) bad = 1;
  }
  if (bad) atomicAnd(&ok, 0);
  __syncthreads();
  if (threadIdx.x==0) flag[0] = ok;
}

// ---------------- prep: unary fp32 -> fp16 ----------------
__global__ __launch_bounds__(256)
void k_cvt(const float* __restrict__ u, __half* __restrict__ u16) {
  size_t q = (size_t)blockIdx.x*256 + threadIdx.x;
  float4 v = reinterpret_cast<const float4*>(u)[q];
  uint2 w; w.x = f2h(v.x, v.y); w.y = f2h(v.z, v.w);
  reinterpret_cast<uint2*>(u16)[q] = w;
}

// ---------------- Q0 = softmax(unary) -> fp16 ----------------
__global__ __launch_bounds__(256)
void k_softmax0(const float* __restrict__ unary, __half* __restrict__ Y) {
  int q = blockIdx.x*256 + threadIdx.x;           // quad id, [0, NPIX/4)
  int b = q >> 16;
  int rem = q & 65535;
  size_t base = (size_t)b*NC*(PLANE>>2) + rem;
  const float4* up = reinterpret_cast<const float4*>(unary);
  float v[NC][4];
  float mx0=-3e38f,mx1=-3e38f,mx2=-3e38f,mx3=-3e38f;
#pragma unroll
  for (int c=0;c<NC;++c) {
    float4 t = up[base + (size_t)c*(PLANE>>2)];
    v[c][0]=t.x; v[c][1]=t.y; v[c][2]=t.z; v[c][3]=t.w;
    mx0=fmaxf(mx0,t.x); mx1=fmaxf(mx1,t.y); mx2=fmaxf(mx2,t.z); mx3=fmaxf(mx3,t.w);
  }
  float s0=0,s1=0,s2=0,s3=0;
#pragma unroll
  for (int c=0;c<NC;++c) {
    float e0=__expf(v[c][0]-mx0), e1=__expf(v[c][1]-mx1);
    float e2=__expf(v[c][2]-mx2), e3=__expf(v[c][3]-mx3);
    v[c][0]=e0; v[c][1]=e1; v[c][2]=e2; v[c][3]=e3;
    s0+=e0; s1+=e1; s2+=e2; s3+=e3;
  }
  float r0=1.f/s0, r1=1.f/s1, r2=1.f/s2, r3=1.f/s3;
  uint2* yp = reinterpret_cast<uint2*>(Y);
#pragma unroll
  for (int c=0;c<NC;++c) {
    uint2 w; w.x=f2h(v[c][0]*r0, v[c][1]*r1); w.y=f2h(v[c][2]*r2, v[c][3]*r3);
    yp[base + (size_t)c*(PLANE>>2)] = w;
  }
}

// ---------------- fused CRF iteration ----------------
// R4: vectorized uint2 staging. R3 post-mortem: phase separation worked
// (687->367us) but staging was 63 scalar 2B loads/thread (G13 violation) and
// WRITE_SIZE still showed ~256MB/iter of spill stores (live set ~105 at the
// 128-VGPR heuristic cap). Now: stage 72-col region x0-4..x0+67 (8B-aligned
// since 64|x0), 20 rows x 18 uint2 = 360 slots -> 1 load + 1 LDS write per
// thread per channel, one (goff,loff,valid) triple precomputed. Vector
// granules never straddle the image edge (4|offset, 4|512) -> whole-vector
// zero-fill for padding. Compute reads shift +2 cols; CROW=72 exactly.

#define LOAD_U2(c, u0,u1) \
  float u0,u1; \
  if (U16) { unsigned int w_ = reinterpret_cast<const unsigned int*>(uptr)[hbase + (size_t)(c)*ch]; \
    float2 t_=h2f(w_); u0=t_.x; u1=t_.y; } \
  else { float2 v_ = reinterpret_cast<const float2*>(uptr)[hbase + (size_t)(c)*ch]; \
    u0=v_.x; u1=v_.y; }

#define ACCUM_COMPAT2(c, a0,a1) \
  float a0=0.f,a1=0.f; \
  _Pragma("unroll") \
  for (int d=0; d<NC; ++d) { float cf_ = compat[(c)*NC+d]; \
    a0 += cf_*msgr[d][0]; a1 += cf_*msgr[d][1]; }

#define CROW 72            // LDS row stride (halves) == staged cols
#define CTILE (20*CROW)    // halves per channel tile (20 rows)

template<bool U16, bool OUTF32>
__global__ __launch_bounds__(512)
void k_iter(const __half* __restrict__ Qin,
            void* __restrict__ Qout,
            const void* __restrict__ uptr,
            const __half* __restrict__ edge16,
            const float* __restrict__ rnorm,
            const float* __restrict__ swp,
            const float* __restrict__ bwp,
            const float* __restrict__ compat,
            const int* __restrict__ flag)
{
  __shared__ __half qt21[NC*CTILE];   // 21 x 20 x 72 halves = 60480 B
  __shared__ __half et[CTILE];        // 20 x 72 halves      =  2880 B

  const int tid = threadIdx.x;
  const int tx = tid & 31;        // 32 threads across 64 px, 2 px each
  const int ty = tid >> 5;        // 16 rows
  const int x0 = blockIdx.x << 6;
  const int y0 = blockIdx.y << 4;
  const int b  = blockIdx.z;

  // ---- staging slot: 20 rows x 18 uint2 (4 halves) = 360 slots ----
  const int slot = tid;
  const int sr = slot / 18;
  const int si = slot - sr*18;
  const int sy = y0 - 2 + sr;                 // rows y0-2 .. y0+17
  const int sx = x0 - 4 + (si<<2);            // cols x0-4 .. x0+67, step 4
  const bool sact = (slot < 360);
  const bool sval = sact && (sy>=0) && (sy<512) && (sx>=0) && (sx<512);
  const int  goff = (sy<<9) + sx;             // halves into plane (use iff sval)
  const int  loff = sr*CROW + (si<<2);        // halves into tile

  const int gy  = y0 + ty;
  const int gx  = x0 + (tx<<1);
  const int pix = (gy<<9) | gx;

  // early independent loads (overlap with staging latency)
  const float2 rn = *reinterpret_cast<const float2*>(rnorm + (size_t)b*PLANE + pix);
  const float sw  = fmaxf(swp[0], 0.f);
  const float bw  = fmaxf(bwp[0], 0.f);
  const int fl = flag[0];

  // ---- memory phase: edge tile + ALL 21 channel tiles, one barrier ----
  {
    const __half* ep = edge16 + (size_t)b*PLANE;
    uint2 w = make_uint2(0u, 0u);
    if (sval) w = *reinterpret_cast<const uint2*>(ep + goff);
    if (sact) *reinterpret_cast<uint2*>(et + loff) = w;
  }
  const __half* qb = Qin + (size_t)b*NC*PLANE;
#pragma unroll
  for (int c=0;c<NC;++c) {
    uint2 w = make_uint2(0u, 0u);
    if (sval) w = *reinterpret_cast<const uint2*>(qb + (size_t)c*PLANE + goff);
    if (sact) *reinterpret_cast<uint2*>(qt21 + c*CTILE + loff) = w;
  }
  __syncthreads();

  const float csw = sw * 0.04f;          // sw/25
  const float b9  = bw * (1.f/9.f);      // bw/9
  const float cb0 = b9*rn.x, cb1 = b9*rn.y;

  const int lx2 = (tx<<1) + 2;           // LDS col of gx-2 (staged region shift)

  // hoist edge window into registers once (channel-invariant):
  // rows ty+1..ty+3, global cols gx-1..gx+2 = staged cols lx2+1..lx2+4
  float ew[3][4];
#pragma unroll
  for (int dy=0;dy<3;++dy) {
    const unsigned int* erow = reinterpret_cast<const unsigned int*>(et + (ty+1+dy)*CROW + lx2);
    float2 e0 = h2f(erow[0]);
    float2 e1 = h2f(erow[1]);
    float2 e2 = h2f(erow[2]);
    ew[dy][0]=e0.y; ew[dy][1]=e1.x; ew[dy][2]=e1.y; ew[dy][3]=e2.x;
  }

  // ---- compute phase: pure LDS reads, no global traffic ----
  float msgr[NC][2];
  const __half* qrow0 = qt21 + ty*CROW + lx2;

#pragma unroll
  for (int c=0;c<NC;++c) {
    float cs0=0,cs1=0,cs2=0,cs3=0,cs4=0,cs5=0;
    float ce0=0,ce1=0,ce2=0,ce3=0;
#pragma unroll
    for (int dy=0;dy<5;++dy) {
      const unsigned int* qrow = reinterpret_cast<const unsigned int*>(qrow0 + c*CTILE + dy*CROW);
      float2 t0 = h2f(qrow[0]);   // gx-2, gx-1
      float2 t1 = h2f(qrow[1]);   // gx  , gx+1
      float2 t2 = h2f(qrow[2]);   // gx+2, gx+3
      cs0+=t0.x; cs1+=t0.y; cs2+=t1.x; cs3+=t1.y; cs4+=t2.x; cs5+=t2.y;
      if (dy>=1 && dy<=3) {
        ce0 += t0.y*ew[dy-1][0];   // gx-1
        ce1 += t1.x*ew[dy-1][1];   // gx
        ce2 += t1.y*ew[dy-1][2];   // gx+1
        ce3 += t2.x*ew[dy-1][3];   // gx+2
      }
    }
    float v0 = cs0+cs1+cs2+cs3+cs4;      // 5-wide window @ gx
    float v1 = v0 - cs0 + cs5;           // @ gx+1
    float w0 = ce0+ce1+ce2;              // 3-wide window @ gx
    float w1 = ce1+ce2+ce3;              // @ gx+1
    msgr[c][0] = csw*v0 + cb0*w0;
    msgr[c][1] = csw*v1 + cb1*w1;
  }

  // ---- phase 2: (optional compat) + softmax over channels, in registers ----
  const size_t hbase = (((size_t)b*NC*PLANE) + (size_t)pix) >> 1;  // half2 / float2 units
  const size_t ch = PLANE >> 1;
  float mx0=-3e38f, mx1=-3e38f;

  if (fl) {   // identity compat fast path
#pragma unroll
    for (int c=0;c<NC;++c) {
      LOAD_U2(c, u0,u1)
      msgr[c][0] = u0 - msgr[c][0];
      msgr[c][1] = u1 - msgr[c][1];
      mx0=fmaxf(mx0,msgr[c][0]); mx1=fmaxf(mx1,msgr[c][1]);
    }
    float s0=0,s1=0;
#pragma unroll
    for (int c=0;c<NC;++c) {
      float e0=__expf(msgr[c][0]-mx0), e1=__expf(msgr[c][1]-mx1);
      msgr[c][0]=e0; msgr[c][1]=e1;
      s0+=e0; s1+=e1;
    }
    float r0=1.f/s0, r1=1.f/s1;
#pragma unroll
    for (int c=0;c<NC;++c) {
      float o0=msgr[c][0]*r0, o1=msgr[c][1]*r1;
      if (OUTF32) {
        reinterpret_cast<float2*>(Qout)[hbase + (size_t)c*ch] = make_float2(o0,o1);
      } else {
        reinterpret_cast<unsigned int*>(Qout)[hbase + (size_t)c*ch] = f2h(o0,o1);
      }
    }
  } else {    // general compat: recompute logits per pass (register-light)
#pragma unroll 1
    for (int c=0;c<NC;++c) {
      ACCUM_COMPAT2(c, a0,a1)
      LOAD_U2(c, u0,u1)
      mx0=fmaxf(mx0,u0-a0); mx1=fmaxf(mx1,u1-a1);
    }
    float s0=0,s1=0;
#pragma unroll 1
    for (int c=0;c<NC;++c) {
      ACCUM_COMPAT2(c, a0,a1)
      LOAD_U2(c, u0,u1)
      s0+=__expf(u0-a0-mx0); s1+=__expf(u1-a1-mx1);
    }
    float r0=1.f/s0, r1=1.f/s1;
#pragma unroll 1
    for (int c=0;c<NC;++c) {
      ACCUM_COMPAT2(c, a0,a1)
      LOAD_U2(c, u0,u1)
      float o0=__expf(u0-a0-mx0)*r0, o1=__expf(u1-a1-mx1)*r1;
      if (OUTF32) {
        reinterpret_cast<float2*>(Qout)[hbase + (size_t)c*ch] = make_float2(o0,o1);
      } else {
        reinterpret_cast<unsigned int*>(Qout)[hbase + (size_t)c*ch] = f2h(o0,o1);
      }
    }
  }
}

extern "C" void kernel_launch(void* const* d_in, const int* in_sizes, int n_in,
                              void* d_out, int out_size, void* d_ws, size_t ws_size,
                              hipStream_t stream)
{
  const float* unary  = (const float*)d_in[0];
  const float* image  = (const float*)d_in[1];
  const float* compat = (const float*)d_in[2];
  const float* swp    = (const float*)d_in[3];
  const float* bwp    = (const float*)d_in[4];

  // ws layout (bytes): X fp16 Q buffer | edge16 | rnorm | flag | (opt) u16
  char* ws = (char*)d_ws;
  __half* X      = (__half*)(ws + 0);            // 88,080,384 B
  __half* edge16 = (__half*)(ws + 88080384);     //  4,194,304 B
  float*  rnorm  = (float*) (ws + 92274688);     //  8,388,608 B
  int*    flag   = (int*)   (ws + 100663296);    //        256 B
  __half* u16    = (__half*)(ws + 100663552);    // 88,080,384 B (optional)
  if (ws_size < (size_t)100663552) return;       // cannot run without scratch
  const bool use_u16 = (ws_size >= (size_t)188743936);

  __half* Y  = (__half*)d_out;   // d_out doubles as fp16 scratch during iters
  float* out = (float*)d_out;

  k_edge   <<<dim3(8192), dim3(256), 0, stream>>>(image, edge16);
  k_rnorm  <<<dim3(8192), dim3(256), 0, stream>>>(edge16, rnorm);
  k_flag   <<<dim3(1),    dim3(256), 0, stream>>>(compat, flag);
  if (use_u16) k_cvt<<<dim3(43008), dim3(256), 0, stream>>>(unary, u16);
  k_softmax0<<<dim3(2048), dim3(256), 0, stream>>>(unary, Y);

  const void* up = use_u16 ? (const void*)u16 : (const void*)unary;
  dim3 gi(8, 32, NB), bi(512);
  // Q0 -> Y(d_out,fp16); odd iters Y->X; even iters X->Y; iter10 X -> d_out fp32
  for (int it = 1; it <= 10; ++it) {
    const __half* qin = (it & 1) ? Y : X;
    if (it == 10) {
      if (use_u16) k_iter<true , true ><<<gi,bi,0,stream>>>(qin,(void*)out,up,edge16,rnorm,swp,bwp,compat,flag);
      else         k_iter<false, true ><<<gi,bi,0,stream>>>(qin,(void*)out,up,edge16,rnorm,swp,bwp,compat,flag);
    } else {
      void* qout = (it & 1) ? (void*)X : (void*)Y;
      if (use_u16) k_iter<true , false><<<gi,bi,0,stream>>>(qin,qout,up,edge16,rnorm,swp,bwp,compat,flag);
      else         k_iter<false, false><<<gi,bi,0,stream>>>(qin,qout,up,edge16,rnorm,swp,bwp,compat,flag);
    }
  }
}